// Round 18
// baseline (86.847 us; speedup 1.0000x reference)
//
#include <hip/hip_runtime.h>
#include <hip/hip_bf16.h>

// Problem constants (match reference)
#define B_    32
#define NV_   50000
#define NF_   100000
#define CCLS  40
#define GPB   128                      // single-wave blocks per batch
#define TPB   64                       // ONE wave per block
#define MT    ((NF_ + 63) / 64)        // 1563 microtiles (64 faces) per batch

#define NLOG2E (-1.44269504088896f)    // folded into pre-sigmoid weights

typedef __attribute__((ext_vector_type(8)))  short short8v;   // 8 bf16 = 4 VGPRs
typedef __attribute__((ext_vector_type(16))) float f32x16;    // MFMA 32x32 accum

__device__ __forceinline__ float frcp(float x)  { return __builtin_amdgcn_rcpf(x); }
// RAW v_exp_f32 (2^x); exp2f() is an ocml libm call (round 12: -20us).
__device__ __forceinline__ float fexp2(float x) { return __builtin_amdgcn_exp2f(x); }

__device__ __forceinline__ ushort f2bf(float x) {
    __hip_bfloat16 h = __float2bfloat16(x);   // RNE
    return *reinterpret_cast<ushort*>(&h);
}

// Kernel 1: the 80us round-11 inner code, repackaged as SINGLE-WAVE blocks
// (TPB=64). The kernel was already wave-autonomous (no main-loop barriers);
// 1-wave workgroups raise the residency unit to the 16-workgroup/CU cap
// (vs ~2.8 observed 4-wave blocks/CU), with the identical instruction stream
// and register pressure. Zero __syncthreads anywhere: same-wave LDS ordering
// via lgkmcnt. sched_barrier(0) at loop top (round 10, anti-spill).
__global__ __launch_bounds__(TPB, 4) void face_mlp_partial(
    const float* __restrict__ V,   // [B,NV,3]
    const int*   __restrict__ F,   // [B,NF,3]
    const float* __restrict__ W1,  // [6,16]
    const float* __restrict__ b1,  // [16]
    const float* __restrict__ W2,  // [16,64]
    const float* __restrict__ b2,  // [64]
    float* __restrict__ ws)        // [B, GPB, 65]
{
    __shared__ __align__(16) ushort myH[64 * 16];   // h1 (2KB, wave-private)
    __shared__ __align__(16) float  myL[64];        // L  (256B)
    __shared__ __align__(16) float  wlds[112];      // -log2e*{W1(96), b1(16)}

    const int i   = blockIdx.x;
    // XCD-aware mapping: block i -> XCD (i&7); each XCD owns 4 batches so the
    // 4 x 600KB V-slices stay resident in its 4MB L2.
    const int xcd = i & 7;
    const int j   = i >> 3;            // 0..511
    const int b   = xcd + 8 * (j >> 7);
    const int g   = j & (GPB - 1);     // 0..127
    const int lane  = threadIdx.x;     // 0..63 (one wave)
    const int ln31  = lane & 31;
    const int halfk = lane >> 5;       // k-half for A/B fragments

    const float* Vb = V + (size_t)b * NV_ * 3;
    const int*   Fb = F + (size_t)b * NF_ * 3;

    // Stage -log2e*W1/b1 (64 threads, 2 rounds). Same-wave: no barrier needed.
    for (int k = lane; k < 112; k += 64)
        wlds[k] = NLOG2E * (k < 96 ? W1[k] : b1[k - 96]);

    // B-fragments of -log2e*W2 (loaded once): lane holds B[k=halfk*8+q][col=n*32+ln31]
    short8v w2f[2];
    float   b2c[2];
#pragma unroll
    for (int n = 0; n < 2; ++n) {
        const int col = n * 32 + ln31;
#pragma unroll
        for (int q = 0; q < 8; ++q)
            w2f[n][q] = (short)f2bf(NLOG2E * W2[(halfk * 8 + q) * 64 + col]);
        b2c[n] = NLOG2E * b2[col];
    }

    float S0 = 0.f, S1 = 0.f, SL = 0.f;

    for (int t = g; t < MT; t += GPB) {
        // Compile-time scheduling fence: nothing moves across the back edge
        // (prevents next-iter gather hoisting -> spill; proven round 10).
        __builtin_amdgcn_sched_barrier(0);

        // ---- Phase A: geometry + layer1; lane owns face = t*64+lane ----
        const int f      = t * 64 + lane;
        const bool valid = (f < NF_);
        const int fi     = valid ? f : 0;

        const int3 fidx = *(const int3*)(Fb + 3 * (size_t)fi);

        const float3 P0 = *(const float3*)(Vb + 3 * (size_t)fidx.x);
        const float3 P1 = *(const float3*)(Vb + 3 * (size_t)fidx.y);
        const float3 P2 = *(const float3*)(Vb + 3 * (size_t)fidx.z);

        const float x0 = (P0.x + P1.x + P2.x) * (1.f / 3.f);
        const float x1 = (P0.y + P1.y + P2.y) * (1.f / 3.f);
        const float x2 = (P0.z + P1.z + P2.z) * (1.f / 3.f);

        const float e1x = P1.x - P0.x, e1y = P1.y - P0.y, e1z = P1.z - P0.z;
        const float e2x = P2.x - P0.x, e2y = P2.y - P0.y, e2z = P2.z - P0.z;

        const float nx = 0.5f * (e1y * e2z - e1z * e2y);
        const float ny = 0.5f * (e1z * e2x - e1x * e2z);
        const float nz = 0.5f * (e1x * e2y - e1y * e2x);

        const float l2 = fmaxf(nx * nx + ny * ny + nz * nz, 1e-6f);
        const float rl = __builtin_amdgcn_rsqf(l2);
        const float L  = valid ? l2 * rl : 0.f;

        const float x3 = nx * rl, x4 = ny * rl, x5 = nz * rl;
        const float xs[6] = {x0, x1, x2, x3, x4, x5};

        short8v hrow[2];
#pragma unroll
        for (int q = 0; q < 4; ++q) {          // 4 channels per group = one quad
            float4 tq = *(const float4*)(wlds + 96 + q * 4);
#pragma unroll
            for (int d = 0; d < 6; ++d) {
                const float4 w = *(const float4*)(wlds + d * 16 + q * 4);
                tq.x = fmaf(xs[d], w.x, tq.x);
                tq.y = fmaf(xs[d], w.y, tq.y);
                tq.z = fmaf(xs[d], w.z, tq.z);
                tq.w = fmaf(xs[d], w.w, tq.w);
            }
            // quad sigmoid: sigma_i = prod_{j!=i} e_j * rcp(prod e_j)
            const float e0 = 1.0f + fexp2(tq.x);
            const float e1 = 1.0f + fexp2(tq.y);
            const float e2 = 1.0f + fexp2(tq.z);
            const float e3 = 1.0f + fexp2(tq.w);
            const float p01 = e0 * e1, p23 = e2 * e3;
            const float rr  = frcp(p01 * p23);
            const float u01 = p23 * rr, u23 = p01 * rr;
            hrow[q >> 1][(q & 1) * 4 + 0] = (short)f2bf(e1 * u01);
            hrow[q >> 1][(q & 1) * 4 + 1] = (short)f2bf(e0 * u01);
            hrow[q >> 1][(q & 1) * 4 + 2] = (short)f2bf(e3 * u23);
            hrow[q >> 1][(q & 1) * 4 + 3] = (short)f2bf(e2 * u23);
        }
        ((short8v*)myH)[lane * 2 + 0] = hrow[0];
        ((short8v*)myH)[lane * 2 + 1] = hrow[1];
        myL[lane] = L;
        SL += L;
        // Same-wave LDS readback below: ordered by lgkmcnt, no barrier.

        // ---- Phase C: layer2 via MFMA on this wave's 64 faces ----
#pragma unroll
        for (int m = 0; m < 2; ++m) {
            const int rowbase = m * 32;
            // A-fragment: row = rowbase+ln31, k-half = halfk
            short8v a = *(const short8v*)(myH + (rowbase + ln31) * 16 + halfk * 8);

            f32x16 c0, c1;
#pragma unroll
            for (int r = 0; r < 16; ++r) { c0[r] = b2c[0]; c1[r] = b2c[1]; }
            c0 = __builtin_amdgcn_mfma_f32_32x32x16_bf16(a, w2f[0], c0, 0, 0, 0);
            c1 = __builtin_amdgcn_mfma_f32_32x32x16_bf16(a, w2f[1], c1, 0, 0, 0);

            // D row mapping: row = (r&3) + 8*(r>>2) + 4*halfk -> contiguous float4
            // (half-wave-uniform addresses -> LDS broadcast)
#pragma unroll
            for (int q = 0; q < 4; ++q) {
                const float4 Lq = *(const float4*)(myL + rowbase + 8 * q + 4 * halfk);
                const float Lv[4] = {Lq.x, Lq.y, Lq.z, Lq.w};
                // two quads over rows (s,s+1): values (c0[r],c1[r],c0[r+1],c1[r+1])
#pragma unroll
                for (int h = 0; h < 2; ++h) {
                    const int r = q * 4 + h * 2;
                    const float e0 = 1.0f + fexp2(c0[r]);
                    const float e1 = 1.0f + fexp2(c1[r]);
                    const float e2 = 1.0f + fexp2(c0[r + 1]);
                    const float e3 = 1.0f + fexp2(c1[r + 1]);
                    const float p01 = e0 * e1, p23 = e2 * e3;
                    const float rr  = frcp(p01 * p23);
                    const float u01 = p23 * rr, u23 = p01 * rr;
                    const float La = Lv[h * 2], Lb = Lv[h * 2 + 1];
                    S0 = fmaf(e1 * u01, La, S0);
                    S1 = fmaf(e0 * u01, La, S1);
                    S0 = fmaf(e3 * u23, Lb, S0);
                    S1 = fmaf(e2 * u23, Lb, S1);
                }
            }
        }
    }

    // ---- Wave reduction (no barrier, no LDS) ----
    // Channel c=n*32+ln31: lanes l and l+32 hold the same channel.
    S0 += __shfl_down(S0, 32, 64);
    S1 += __shfl_down(S1, 32, 64);
#pragma unroll
    for (int off = 32; off; off >>= 1)
        SL += __shfl_down(SL, off, 64);

    float* wsg = ws + ((size_t)b * GPB + g) * 65;
    if (lane < 32) {
        wsg[ln31]      = S0;
        wsg[32 + ln31] = S1;
    }
    if (lane == 0) wsg[64] = SL;
}

// Kernel 2: fold the GPB partials through W3/b3. One block per batch.
__global__ __launch_bounds__(128) void finalize_out(
    const float* __restrict__ ws,  // [B, GPB, 65]
    const float* __restrict__ W3,  // [64, CCLS]
    const float* __restrict__ b3,  // [CCLS]
    float* __restrict__ out)       // [B, CCLS]
{
    __shared__ float sm[65];
    const int b = blockIdx.x;
    const int tid = threadIdx.x;

    if (tid < 65) {
        float s = 0.f;
#pragma unroll 8
        for (int g = 0; g < GPB; ++g)
            s += ws[((size_t)b * GPB + g) * 65 + tid];
        sm[tid] = s;
    }
    __syncthreads();

    if (tid < CCLS) {
        float acc = b3[tid] * sm[64];
#pragma unroll
        for (int k = 0; k < 64; ++k)
            acc = fmaf(sm[k], W3[k * CCLS + tid], acc);
        out[b * CCLS + tid] = acc;
    }
}

extern "C" void kernel_launch(void* const* d_in, const int* in_sizes, int n_in,
                              void* d_out, int out_size, void* d_ws, size_t ws_size,
                              hipStream_t stream) {
    const float* V  = (const float*)d_in[0];
    const int*   F  = (const int*)  d_in[1];
    const float* W1 = (const float*)d_in[2];
    const float* b1 = (const float*)d_in[3];
    const float* W2 = (const float*)d_in[4];
    const float* b2 = (const float*)d_in[5];
    const float* W3 = (const float*)d_in[6];
    const float* b3 = (const float*)d_in[7];
    float* out = (float*)d_out;
    float* ws  = (float*)d_ws;     // needs B*GPB*65*4 = 1,064,960 bytes

    face_mlp_partial<<<B_ * GPB, TPB, 0, stream>>>(V, F, W1, b1, W2, b2, ws);
    finalize_out<<<B_, 128, 0, stream>>>(ws, W3, b3, out);
}

// Round 19
// 79.060 us; speedup vs baseline: 1.0985x; 1.0985x over previous
//
#include <hip/hip_runtime.h>
#include <hip/hip_bf16.h>

// Problem constants (match reference)
#define B_    32
#define NV_   50000
#define NF_   100000
#define CCLS  40
#define GPB   64                       // blocks per batch
#define TPB   256
#define MT    ((NF_ + 63) / 64)        // 1563 microtiles (64 faces) per batch
#define WSLOT (GPB * 4)                // 256 wave-slots per batch

#define NLOG2E (-1.44269504088896f)    // folded into pre-sigmoid weights

typedef __attribute__((ext_vector_type(8)))  short short8v;   // 8 bf16 = 4 VGPRs
typedef __attribute__((ext_vector_type(16))) float f32x16;    // MFMA 32x32 accum

__device__ __forceinline__ float frcp(float x)  { return __builtin_amdgcn_rcpf(x); }
__device__ __forceinline__ float fexp2(float x) { return __builtin_amdgcn_exp2f(x); }

__device__ __forceinline__ ushort f2bf(float x) {
    __hip_bfloat16 h = __float2bfloat16(x);   // RNE
    return *reinterpret_cast<ushort*>(&h);
}

// Kernel 1: round-11 optimum (79.8us) + manual 1-deep gather pipeline.
// Wave-autonomous 64-face microtiles via private LDS; sched_barrier(0) at
// loop top (anti-spill, round 10). Each iteration consumes vertex data
// prefetched by the PREVIOUS iteration: next F-load issues before the
// layer-1 sigmoid block (~800cy cover), next V-loads issue before phase C
// (~1600cy cover). Bounded +12 live regs -> stays in the 4-wave bucket.
__global__ __launch_bounds__(TPB, 4) void face_mlp_partial(
    const float* __restrict__ V,   // [B,NV,3]
    const int*   __restrict__ F,   // [B,NF,3]
    const float* __restrict__ W1,  // [6,16]
    const float* __restrict__ b1,  // [16]
    const float* __restrict__ W2,  // [16,64]
    const float* __restrict__ b2,  // [64]
    float* __restrict__ ws)        // [B, GPB, 65]
{
    __shared__ __align__(16) ushort h1w[4][64 * 16]; // wave-private h1 (8KB)
    __shared__ __align__(16) float  sLw[4][64];      // wave-private L (1KB)
    __shared__ __align__(16) float  wlds[112];       // -log2e*{W1(96), b1(16)}
    __shared__ float red[4][64];
    __shared__ float slred[4];

    const int i   = blockIdx.x;
    // XCD-aware mapping: block i -> XCD (i&7); each XCD owns 4 batches so the
    // 4 x 600KB V-slices stay resident in its 4MB L2.
    const int xcd = i & 7;
    const int j   = i >> 3;
    const int b   = xcd + 8 * (j >> 6);
    const int g   = j & 63;
    const int tid = threadIdx.x;
    const int lane  = tid & 63;
    const int wave  = tid >> 6;
    const int ln31  = lane & 31;
    const int halfk = lane >> 5;       // k-half for A/B fragments

    const float* Vb = V + (size_t)b * NV_ * 3;
    const int*   Fb = F + (size_t)b * NF_ * 3;

    if (tid < 96)       wlds[tid] = NLOG2E * W1[tid];
    else if (tid < 112) wlds[tid] = NLOG2E * b1[tid - 96];

    // B-fragments of -log2e*W2 (loaded once): lane holds B[k=halfk*8+q][col=n*32+ln31]
    short8v w2f[2];
    float   b2c[2];
#pragma unroll
    for (int n = 0; n < 2; ++n) {
        const int col = n * 32 + ln31;
#pragma unroll
        for (int q = 0; q < 8; ++q)
            w2f[n][q] = (short)f2bf(NLOG2E * W2[(halfk * 8 + q) * 64 + col]);
        b2c[n] = NLOG2E * b2[col];
    }

    float S0 = 0.f, S1 = 0.f, SL = 0.f;
    ushort* myH = h1w[wave];
    float*  myL = sLw[wave];

    __syncthreads();                   // wlds visible (only pre-loop barrier)

    const int wslot = g * 4 + wave;    // 0..WSLOT-1

    // ---- Pipeline prologue: load tile wslot's face + vertices ----
    float3 P0, P1, P2;
    {
        const int f0  = wslot * 64 + lane;
        const int fi0 = (f0 < NF_) ? f0 : 0;
        const int3 fx = *(const int3*)(Fb + 3 * (size_t)fi0);
        P0 = *(const float3*)(Vb + 3 * (size_t)fx.x);
        P1 = *(const float3*)(Vb + 3 * (size_t)fx.y);
        P2 = *(const float3*)(Vb + 3 * (size_t)fx.z);
    }

    for (int t = wslot; t < MT; t += WSLOT) {
        // Compile-time scheduling fence: nothing moves across the back edge
        // (prevents unbounded gather hoisting -> spill; proven round 10).
        __builtin_amdgcn_sched_barrier(0);

        const bool valid = (t * 64 + lane < NF_);

        // ---- geometry from prefetched P0..P2 ----
        const float x0 = (P0.x + P1.x + P2.x) * (1.f / 3.f);
        const float x1 = (P0.y + P1.y + P2.y) * (1.f / 3.f);
        const float x2 = (P0.z + P1.z + P2.z) * (1.f / 3.f);

        const float e1x = P1.x - P0.x, e1y = P1.y - P0.y, e1z = P1.z - P0.z;
        const float e2x = P2.x - P0.x, e2y = P2.y - P0.y, e2z = P2.z - P0.z;

        const float nx = 0.5f * (e1y * e2z - e1z * e2y);
        const float ny = 0.5f * (e1z * e2x - e1x * e2z);
        const float nz = 0.5f * (e1x * e2y - e1y * e2x);

        const float l2 = fmaxf(nx * nx + ny * ny + nz * nz, 1e-6f);
        const float rl = __builtin_amdgcn_rsqf(l2);
        const float L  = valid ? l2 * rl : 0.f;

        const float x3 = nx * rl, x4 = ny * rl, x5 = nz * rl;
        const float xs[6] = {x0, x1, x2, x3, x4, x5};

        // ---- issue NEXT tile's face-index load (covered by layer1 below) ----
        const int tn  = t + WSLOT;
        const int fn  = tn * 64 + lane;
        const int fni = (tn < MT && fn < NF_) ? fn : 0;
        const int3 nfx = *(const int3*)(Fb + 3 * (size_t)fni);

        // ---- layer1 + sigmoids ----
        short8v hrow[2];
#pragma unroll
        for (int q = 0; q < 4; ++q) {          // 4 channels per group = one quad
            float4 tq = *(const float4*)(wlds + 96 + q * 4);
#pragma unroll
            for (int d = 0; d < 6; ++d) {
                const float4 w = *(const float4*)(wlds + d * 16 + q * 4);
                tq.x = fmaf(xs[d], w.x, tq.x);
                tq.y = fmaf(xs[d], w.y, tq.y);
                tq.z = fmaf(xs[d], w.z, tq.z);
                tq.w = fmaf(xs[d], w.w, tq.w);
            }
            // quad sigmoid: sigma_i = prod_{j!=i} e_j * rcp(prod e_j)
            const float e0 = 1.0f + fexp2(tq.x);
            const float e1 = 1.0f + fexp2(tq.y);
            const float e2 = 1.0f + fexp2(tq.z);
            const float e3 = 1.0f + fexp2(tq.w);
            const float p01 = e0 * e1, p23 = e2 * e3;
            const float rr  = frcp(p01 * p23);
            const float u01 = p23 * rr, u23 = p01 * rr;
            hrow[q >> 1][(q & 1) * 4 + 0] = (short)f2bf(e1 * u01);
            hrow[q >> 1][(q & 1) * 4 + 1] = (short)f2bf(e0 * u01);
            hrow[q >> 1][(q & 1) * 4 + 2] = (short)f2bf(e3 * u23);
            hrow[q >> 1][(q & 1) * 4 + 3] = (short)f2bf(e2 * u23);
        }
        ((short8v*)myH)[lane * 2 + 0] = hrow[0];
        ((short8v*)myH)[lane * 2 + 1] = hrow[1];
        myL[lane] = L;
        SL += L;

        // ---- issue NEXT tile's vertex loads (covered by phase C below) ----
        const float3 N0 = *(const float3*)(Vb + 3 * (size_t)nfx.x);
        const float3 N1 = *(const float3*)(Vb + 3 * (size_t)nfx.y);
        const float3 N2 = *(const float3*)(Vb + 3 * (size_t)nfx.z);

        // ---- Phase C: layer2 via MFMA on this wave's 64 faces ----
#pragma unroll
        for (int m = 0; m < 2; ++m) {
            const int rowbase = m * 32;
            // A-fragment: row = rowbase+ln31, k-half = halfk
            short8v a = *(const short8v*)(myH + (rowbase + ln31) * 16 + halfk * 8);

            f32x16 c0, c1;
#pragma unroll
            for (int r = 0; r < 16; ++r) { c0[r] = b2c[0]; c1[r] = b2c[1]; }
            c0 = __builtin_amdgcn_mfma_f32_32x32x16_bf16(a, w2f[0], c0, 0, 0, 0);
            c1 = __builtin_amdgcn_mfma_f32_32x32x16_bf16(a, w2f[1], c1, 0, 0, 0);

            // D row mapping: row = (r&3) + 8*(r>>2) + 4*halfk -> contiguous float4
#pragma unroll
            for (int q = 0; q < 4; ++q) {
                const float4 Lq = *(const float4*)(myL + rowbase + 8 * q + 4 * halfk);
                const float Lv[4] = {Lq.x, Lq.y, Lq.z, Lq.w};
#pragma unroll
                for (int h = 0; h < 2; ++h) {
                    const int r = q * 4 + h * 2;
                    const float e0 = 1.0f + fexp2(c0[r]);
                    const float e1 = 1.0f + fexp2(c1[r]);
                    const float e2 = 1.0f + fexp2(c0[r + 1]);
                    const float e3 = 1.0f + fexp2(c1[r + 1]);
                    const float p01 = e0 * e1, p23 = e2 * e3;
                    const float rr  = frcp(p01 * p23);
                    const float u01 = p23 * rr, u23 = p01 * rr;
                    const float La = Lv[h * 2], Lb = Lv[h * 2 + 1];
                    S0 = fmaf(e1 * u01, La, S0);
                    S1 = fmaf(e0 * u01, La, S1);
                    S0 = fmaf(e3 * u23, Lb, S0);
                    S1 = fmaf(e2 * u23, Lb, S1);
                }
            }
        }

        // ---- rotate pipeline registers ----
        P0 = N0; P1 = N1; P2 = N2;
    }

    // ---- Block reduction (single barrier) ----
    // Channel c=n*32+ln31: lanes l and l+32 hold the same channel.
    S0 += __shfl_down(S0, 32, 64);
    S1 += __shfl_down(S1, 32, 64);
#pragma unroll
    for (int off = 32; off; off >>= 1)
        SL += __shfl_down(SL, off, 64);

    if (lane < 32) {
        red[wave][ln31]      = S0;
        red[wave][32 + ln31] = S1;
    }
    if (lane == 0) slred[wave] = SL;
    __syncthreads();

    if (tid < 64) {
        float s = red[0][tid] + red[1][tid] + red[2][tid] + red[3][tid];
        ws[((size_t)b * GPB + g) * 65 + tid] = s;
    }
    if (tid == 0)
        ws[((size_t)b * GPB + g) * 65 + 64] = slred[0] + slred[1] + slred[2] + slred[3];
}

// Kernel 2: fold the GPB partials through W3/b3. One block per batch.
__global__ __launch_bounds__(128) void finalize_out(
    const float* __restrict__ ws,  // [B, GPB, 65]
    const float* __restrict__ W3,  // [64, CCLS]
    const float* __restrict__ b3,  // [CCLS]
    float* __restrict__ out)       // [B, CCLS]
{
    __shared__ float sm[65];
    const int b = blockIdx.x;
    const int tid = threadIdx.x;

    if (tid < 65) {
        float s = 0.f;
#pragma unroll 8
        for (int g = 0; g < GPB; ++g)
            s += ws[((size_t)b * GPB + g) * 65 + tid];
        sm[tid] = s;
    }
    __syncthreads();

    if (tid < CCLS) {
        float acc = b3[tid] * sm[64];
#pragma unroll
        for (int k = 0; k < 64; ++k)
            acc = fmaf(sm[k], W3[k * CCLS + tid], acc);
        out[b * CCLS + tid] = acc;
    }
}

extern "C" void kernel_launch(void* const* d_in, const int* in_sizes, int n_in,
                              void* d_out, int out_size, void* d_ws, size_t ws_size,
                              hipStream_t stream) {
    const float* V  = (const float*)d_in[0];
    const int*   F  = (const int*)  d_in[1];
    const float* W1 = (const float*)d_in[2];
    const float* b1 = (const float*)d_in[3];
    const float* W2 = (const float*)d_in[4];
    const float* b2 = (const float*)d_in[5];
    const float* W3 = (const float*)d_in[6];
    const float* b3 = (const float*)d_in[7];
    float* out = (float*)d_out;
    float* ws  = (float*)d_ws;     // needs B*GPB*65*4 = 532,480 bytes

    face_mlp_partial<<<B_ * GPB, TPB, 0, stream>>>(V, F, W1, b1, W2, b2, ws);
    finalize_out<<<B_, 128, 0, stream>>>(ws, W3, b3, out);
}